// Round 6
// baseline (6917.445 us; speedup 1.0000x reference)
//
#include <hip/hip_runtime.h>
#include <stdint.h>
#include <math.h>

// Problem constants
#define NTOK 4096   // B*S
#define H    1024
#define NHEAD 16
#define HD   64
#define SEQ  2048
#define NE   8
#define DDIM 1024

// ---------------- helpers ----------------

__device__ __forceinline__ int dot4(int a, int b, int c) {
#if __has_builtin(__builtin_amdgcn_sdot4)
  return __builtin_amdgcn_sdot4(a, b, c, false);
#else
  c += (int)(int8_t)(a)       * (int)(int8_t)(b);
  c += (int)(int8_t)(a >> 8)  * (int)(int8_t)(b >> 8);
  c += (int)(int8_t)(a >> 16) * (int)(int8_t)(b >> 16);
  c += (int)(int8_t)(a >> 24) * (int)(int8_t)(b >> 24);
  return c;
#endif
}

// 256-thread block reduce (double). op=0 sum, op=1 max. tmp: __shared__ double[4]
__device__ __forceinline__ double bredd(double v, int op, double* tmp) {
#pragma unroll
  for (int o = 32; o; o >>= 1) {
    double w = __shfl_xor(v, o);
    v = op ? fmax(v, w) : v + w;
  }
  int wid = threadIdx.x >> 6;
  if ((threadIdx.x & 63) == 0) tmp[wid] = v;
  __syncthreads();
  double r = op ? fmax(fmax(tmp[0], tmp[1]), fmax(tmp[2], tmp[3]))
                : (tmp[0] + tmp[1] + tmp[2] + tmp[3]);
  __syncthreads();
  return r;
}

// quantize 4 doubles to packed int8 with double scale (round-half-even like jnp.round)
__device__ __forceinline__ int qpackd(double n0, double n1, double n2, double n3, double s) {
  int a = (int)fmin(fmax(rint(n0 * s), -128.0), 127.0);
  int b = (int)fmin(fmax(rint(n1 * s), -128.0), 127.0);
  int c = (int)fmin(fmax(rint(n2 * s), -128.0), 127.0);
  int d = (int)fmin(fmax(rint(n3 * s), -128.0), 127.0);
  return (a & 255) | ((b & 255) << 8) | ((c & 255) << 16) | ((d & 255) << 24);
}

// map flat tensor id (0..27, each 1M elems) -> source pointer
__device__ __forceinline__ const float* wsrc(int tensor,
    const float* qw_, const float* kw_, const float* vw_, const float* ow_,
    const float* gw_, const float* uw_, const float* dw_) {
  if (tensor < 4) return tensor == 0 ? qw_ : tensor == 1 ? kw_ : tensor == 2 ? vw_ : ow_;
  if (tensor < 12) return gw_ + ((long long)(tensor - 4) << 20);
  if (tensor < 20) return uw_ + ((long long)(tensor - 12) << 20);
  return dw_ + ((long long)(tensor - 20) << 20);
}

// ---------------- weight quantization (fp64 scale, deterministic) ----------------

__global__ __launch_bounds__(256) void k_absum(
    const float* qw_, const float* kw_, const float* vw_, const float* ow_,
    const float* gw_, const float* uw_, const float* dw_, double* partial) {
  __shared__ double tmp[4];
  int tensor = blockIdx.x >> 10;
  int j = ((blockIdx.x & 1023) << 10) + threadIdx.x * 4;
  const float* src = wsrc(tensor, qw_, kw_, vw_, ow_, gw_, uw_, dw_);
  float4 w = *(const float4*)(src + j);
  double v = fabs((double)w.x) + fabs((double)w.y) + fabs((double)w.z) + fabs((double)w.w);
  v = bredd(v, 0, tmp);
  if (threadIdx.x == 0) partial[blockIdx.x] = v;
}

__global__ __launch_bounds__(256) void k_wscale(const double* partial, double* wsd) {
  __shared__ double tmp[4];
  int tensor = blockIdx.x;
  const double* p = partial + (tensor << 10);
  int i = threadIdx.x * 4;
  double v = p[i] + p[i + 1] + p[i + 2] + p[i + 3];
  v = bredd(v, 0, tmp);
  if (threadIdx.x == 0) wsd[tensor] = 1.0 / fmax(v * (1.0 / 1048576.0), 1e-5);
}

__global__ __launch_bounds__(256) void k_quantw(
    const float* qw_, const float* kw_, const float* vw_, const float* ow_,
    const float* gw_, const float* uw_, const float* dw_,
    const double* wsd, int8_t* qw) {
  int tensor = blockIdx.x >> 10;
  int j = ((blockIdx.x & 1023) << 10) + threadIdx.x * 4;
  const float* src = wsrc(tensor, qw_, kw_, vw_, ow_, gw_, uw_, dw_);
  double s = wsd[tensor];
  float4 w = *(const float4*)(src + j);
  int a = (int)fmin(fmax(rint((double)w.x * s), -1.0), 1.0);
  int b = (int)fmin(fmax(rint((double)w.y * s), -1.0), 1.0);
  int c = (int)fmin(fmax(rint((double)w.z * s), -1.0), 1.0);
  int d = (int)fmin(fmax(rint((double)w.w * s), -1.0), 1.0);
  ((int*)qw)[(tensor << 18) + (j >> 2)] =
      (a & 255) | ((b & 255) << 8) | ((c & 255) << 16) | ((d & 255) << 24);
}

// ---------------- rmsnorm + act_quant (attention input), fp64 decisions ----------------

__global__ __launch_bounds__(256) void k_rms1(const float* X, const float* lnw,
                                              int8_t* xq, double* xsd) {
  __shared__ double tmp[4];
  int t = blockIdx.x, tid = threadIdx.x;
  float4 xv = ((const float4*)(X + (long long)t * H))[tid];
  double x0 = xv.x, x1 = xv.y, x2 = xv.z, x3 = xv.w;
  double ss = x0 * x0 + x1 * x1 + x2 * x2 + x3 * x3;
  ss = bredd(ss, 0, tmp);
  double r = 1.0 / sqrt(ss * (1.0 / 1024.0) + 1e-5);
  float4 wv = ((const float4*)lnw)[tid];
  double n0 = x0 * r * wv.x, n1 = x1 * r * wv.y, n2 = x2 * r * wv.z, n3 = x3 * r * wv.w;
  double ma = fmax(fmax(fabs(n0), fabs(n1)), fmax(fabs(n2), fabs(n3)));
  ma = bredd(ma, 1, tmp);
  double s = 127.0 / fmax(ma, 1e-5);
  ((int*)xq)[t * 256 + tid] = qpackd(n0, n1, n2, n3, s);
  if (tid == 0) xsd[t] = s;
}

// act_quant only (rows of 1024 floats), fp64 decisions
__global__ __launch_bounds__(256) void k_actq(const float* X, int8_t* xq, double* xsd) {
  __shared__ double tmp[4];
  int t = blockIdx.x, tid = threadIdx.x;
  float4 xv = ((const float4*)(X + (long long)t * H))[tid];
  double x0 = xv.x, x1 = xv.y, x2 = xv.z, x3 = xv.w;
  double ma = fmax(fmax(fabs(x0), fabs(x1)), fmax(fabs(x2), fabs(x3)));
  ma = bredd(ma, 1, tmp);
  double s = 127.0 / fmax(ma, 1e-5);
  ((int*)xq)[t * 256 + tid] = qpackd(x0, x1, x2, x3, s);
  if (tid == 0) xsd[t] = s;
}

// ---------------- int8 GEMM: out[t,n] = res[t,n] + acc / (xs[t]*sw) ----------------
// k-major LDS tiles: inner loop reads 2x ds_read_b128 per kk.

__global__ __launch_bounds__(256) void k_gemm(
    const int8_t* __restrict__ Xq, const double* __restrict__ xsd,
    const int8_t* __restrict__ W, const double* __restrict__ wsd, int widx,
    const float* __restrict__ residual, float* __restrict__ out) {
  __shared__ int Xs[32][65];
  __shared__ int Wt[32][65];
  int tid = threadIdx.x;
  int t0 = blockIdx.y * 64, n0 = blockIdx.x * 64;
  const int* Xg = (const int*)Xq;
  const int* Wg = (const int*)W;
  int acc[4][4] = {};
  int lr = tid >> 5, lc = tid & 31;
  int ty = tid >> 4, tx = tid & 15;
  for (int k0 = 0; k0 < 1024; k0 += 128) {
    int kc = k0 >> 2;
#pragma unroll
    for (int i = 0; i < 8; i++) {
      int rr = lr + i * 8;
      Xs[lc][rr] = Xg[(t0 + rr) * 256 + kc + lc];
      Wt[lc][rr] = Wg[(n0 + rr) * 256 + kc + lc];
    }
    __syncthreads();
#pragma unroll
    for (int kk = 0; kk < 32; kk++) {
      int4 a = *(const int4*)&Xs[kk][ty * 4];
      int4 b = *(const int4*)&Wt[kk][tx * 4];
      acc[0][0] = dot4(a.x, b.x, acc[0][0]); acc[0][1] = dot4(a.x, b.y, acc[0][1]);
      acc[0][2] = dot4(a.x, b.z, acc[0][2]); acc[0][3] = dot4(a.x, b.w, acc[0][3]);
      acc[1][0] = dot4(a.y, b.x, acc[1][0]); acc[1][1] = dot4(a.y, b.y, acc[1][1]);
      acc[1][2] = dot4(a.y, b.z, acc[1][2]); acc[1][3] = dot4(a.y, b.w, acc[1][3]);
      acc[2][0] = dot4(a.z, b.x, acc[2][0]); acc[2][1] = dot4(a.z, b.y, acc[2][1]);
      acc[2][2] = dot4(a.z, b.z, acc[2][2]); acc[2][3] = dot4(a.z, b.w, acc[2][3]);
      acc[3][0] = dot4(a.w, b.x, acc[3][0]); acc[3][1] = dot4(a.w, b.y, acc[3][1]);
      acc[3][2] = dot4(a.w, b.z, acc[3][2]); acc[3][3] = dot4(a.w, b.w, acc[3][3]);
    }
    __syncthreads();
  }
  double sw = wsd[widx];
#pragma unroll
  for (int i = 0; i < 4; i++) {
    int t = t0 + ty * 4 + i;
    double inv = 1.0 / (xsd[t] * sw);
#pragma unroll
    for (int j = 0; j < 4; j++) {
      int n = n0 + tx * 4 + j;
      double v = (double)acc[i][j] * inv;
      if (residual) v += (double)residual[(long long)t * H + n];
      out[(long long)t * H + n] = (float)v;
    }
  }
}

// ---------------- attention ----------------
// k_knorm: per-(b,head) max key L2-norm -> fixed softmax bound.

__global__ __launch_bounds__(256) void k_knorm(const float* __restrict__ K,
                                               float* __restrict__ Mk) {
  __shared__ float tmp[4];
  int bh = blockIdx.x;          // b*16 + head
  int b = bh >> 4, head = bh & 15;
  int tid = threadIdx.x;
  float mx = 0.f;
  for (int key = tid; key < SEQ; key += 256) {
    const float4* kr = (const float4*)(K + ((long long)(b * SEQ + key)) * H + head * HD);
    float s = 0.f;
#pragma unroll
    for (int i = 0; i < 16; i++) {
      float4 v = kr[i];
      s += v.x * v.x + v.y * v.y + v.z * v.z + v.w * v.w;
    }
    mx = fmaxf(mx, s);
  }
#pragma unroll
  for (int o = 32; o; o >>= 1) mx = fmaxf(mx, __shfl_xor(mx, o));
  if ((tid & 63) == 0) tmp[tid >> 6] = mx;
  __syncthreads();
  if (tid == 0)
    Mk[bh] = sqrtf(fmaxf(fmaxf(tmp[0], tmp[1]), fmaxf(tmp[2], tmp[3])));
}

// k_attn: grid (32 qtiles reversed, 16 heads, 2 b), block 256 = 4 waves.
// Block covers 64 queries; the 4 waves split the KEY tiles (t % 4 == w) of the
// SAME queries -> 4096 waves = 4 waves/SIMD. Lane = quad*4+dp: quad owns
// queries qlo+quad*4..+3, dp owns dims [dp*16, +16). K/V read directly from
// global (broadcast-coalesced, L1/L2-served) -- NO LDS staging, NO barriers in
// the hot loop. Softmax uses a FIXED per-query bound mb = 0.125*|q|*maxk|k|
// (Cauchy-Schwarz: p <= mb always; shift-invariance keeps the result exact) so
// there is no online-max serial chain and wave partials merge by plain sums.

__global__ __launch_bounds__(256, 4) void k_attn(
    const float* __restrict__ Q, const float* __restrict__ K,
    const float* __restrict__ V, float* __restrict__ O,
    const float* __restrict__ Mk) {
  __shared__ float mrg[2][64][68];   // 34816 B: acc merge buffers
  __shared__ float lsh[4][64];       // l partials
  int g = 31 - blockIdx.x;           // longest blocks dispatch first
  int head = blockIdx.y, b = blockIdx.z;
  int tid = threadIdx.x;
  int w = tid >> 6, lane = tid & 63;
  int quad = lane >> 2, dp = lane & 3;
  int qlo = g * 64;
  int d0 = dp << 4;
  long long bh_base = ((long long)b * SEQ) * H + head * HD;

  float4 q[4][4];
  float mb[4], l[4] = {0.f, 0.f, 0.f, 0.f};
  float acc[4][16];
#pragma unroll
  for (int qq = 0; qq < 4; qq++)
#pragma unroll
    for (int i = 0; i < 16; i++) acc[qq][i] = 0.f;
  float mkv = Mk[b * 16 + head];
#pragma unroll
  for (int qq = 0; qq < 4; qq++) {
    int sq = qlo + quad * 4 + qq;
    const float4* qp = (const float4*)(Q + bh_base + (long long)sq * H + d0);
    float ss = 0.f;
#pragma unroll
    for (int i = 0; i < 4; i++) {
      float4 t = qp[i];
      q[qq][i] = make_float4(t.x * 0.125f, t.y * 0.125f, t.z * 0.125f, t.w * 0.125f);
      ss += t.x * t.x + t.y * t.y + t.z * t.z + t.w * t.w;
    }
    ss += __shfl_xor(ss, 1);
    ss += __shfl_xor(ss, 2);
    mb[qq] = 0.125f * sqrtf(ss) * mkv;
  }

  // key tiles t = w, w+4, ...; tiles < g are unmasked, tile g is diagonal
  for (int t = w; t <= g; t += 4) {
    const float* kp = K + bh_base + (long long)(t * 64) * H + d0;
    const float* vp = V + bh_base + (long long)(t * 64) * H + d0;
    if (t < g) {
#pragma unroll 2
      for (int kk = 0; kk < 64; kk++) {
        float4 kvv[4], vvv[4];
#pragma unroll
        for (int i = 0; i < 4; i++) kvv[i] = ((const float4*)kp)[i];
#pragma unroll
        for (int i = 0; i < 4; i++) vvv[i] = ((const float4*)vp)[i];
        kp += H; vp += H;
#pragma unroll
        for (int qq = 0; qq < 4; qq++) {
          float pa = 0.f, pb = 0.f;
#pragma unroll
          for (int i = 0; i < 4; i++) {
            pa = fmaf(q[qq][i].x, kvv[i].x, pa);
            pb = fmaf(q[qq][i].y, kvv[i].y, pb);
            pa = fmaf(q[qq][i].z, kvv[i].z, pa);
            pb = fmaf(q[qq][i].w, kvv[i].w, pb);
          }
          float p = pa + pb;
          p += __shfl_xor(p, 1);
          p += __shfl_xor(p, 2);
          float wgt = __expf(p - mb[qq]);
          l[qq] += wgt;
#pragma unroll
          for (int i = 0; i < 4; i++) {
            acc[qq][4*i+0] = fmaf(wgt, vvv[i].x, acc[qq][4*i+0]);
            acc[qq][4*i+1] = fmaf(wgt, vvv[i].y, acc[qq][4*i+1]);
            acc[qq][4*i+2] = fmaf(wgt, vvv[i].z, acc[qq][4*i+2]);
            acc[qq][4*i+3] = fmaf(wgt, vvv[i].w, acc[qq][4*i+3]);
          }
        }
      }
    } else {
      // diagonal tile: local query index quad*4+qq sees local keys kk <= that
      for (int kk = 0; kk < 64; kk++) {
        float4 kvv[4], vvv[4];
#pragma unroll
        for (int i = 0; i < 4; i++) kvv[i] = ((const float4*)kp)[i];
#pragma unroll
        for (int i = 0; i < 4; i++) vvv[i] = ((const float4*)vp)[i];
        kp += H; vp += H;
#pragma unroll
        for (int qq = 0; qq < 4; qq++) {
          float pa = 0.f, pb = 0.f;
#pragma unroll
          for (int i = 0; i < 4; i++) {
            pa = fmaf(q[qq][i].x, kvv[i].x, pa);
            pb = fmaf(q[qq][i].y, kvv[i].y, pb);
            pa = fmaf(q[qq][i].z, kvv[i].z, pa);
            pb = fmaf(q[qq][i].w, kvv[i].w, pb);
          }
          float p = pa + pb;
          p += __shfl_xor(p, 1);
          p += __shfl_xor(p, 2);
          float wgt = (kk <= quad * 4 + qq) ? __expf(p - mb[qq]) : 0.f;
          l[qq] += wgt;
#pragma unroll
          for (int i = 0; i < 4; i++) {
            acc[qq][4*i+0] = fmaf(wgt, vvv[i].x, acc[qq][4*i+0]);
            acc[qq][4*i+1] = fmaf(wgt, vvv[i].y, acc[qq][4*i+1]);
            acc[qq][4*i+2] = fmaf(wgt, vvv[i].z, acc[qq][4*i+2]);
            acc[qq][4*i+3] = fmaf(wgt, vvv[i].w, acc[qq][4*i+3]);
          }
        }
      }
    }
  }

  // ---- merge: fixed bound per query => partials sum directly ----
  if (dp == 0) {
#pragma unroll
    for (int qq = 0; qq < 4; qq++) lsh[w][quad * 4 + qq] = l[qq];
  }
  if (w & 1) {                       // waves 1,3 write buffers 0,1
    int buf = w >> 1;
#pragma unroll
    for (int qq = 0; qq < 4; qq++) {
      float4* dst = (float4*)&mrg[buf][quad * 4 + qq][d0];
#pragma unroll
      for (int i = 0; i < 4; i++)
        dst[i] = make_float4(acc[qq][4*i], acc[qq][4*i+1], acc[qq][4*i+2], acc[qq][4*i+3]);
    }
  }
  __syncthreads();
  if (!(w & 1)) {                    // waves 0,2 add buffers 0,1
    int buf = w >> 1;
#pragma unroll
    for (int qq = 0; qq < 4; qq++) {
      const float4* src = (const float4*)&mrg[buf][quad * 4 + qq][d0];
#pragma unroll
      for (int i = 0; i < 4; i++) {
        float4 s = src[i];
        acc[qq][4*i+0] += s.x; acc[qq][4*i+1] += s.y;
        acc[qq][4*i+2] += s.z; acc[qq][4*i+3] += s.w;
      }
    }
  }
  __syncthreads();
  if (w == 2) {                      // wave 2 writes its sum to buffer 0
#pragma unroll
    for (int qq = 0; qq < 4; qq++) {
      float4* dst = (float4*)&mrg[0][quad * 4 + qq][d0];
#pragma unroll
      for (int i = 0; i < 4; i++)
        dst[i] = make_float4(acc[qq][4*i], acc[qq][4*i+1], acc[qq][4*i+2], acc[qq][4*i+3]);
    }
  }
  __syncthreads();
  if (w == 0) {                      // wave 0: final sum, normalize, store
#pragma unroll
    for (int qq = 0; qq < 4; qq++) {
      int j = quad * 4 + qq;
      const float4* src = (const float4*)&mrg[0][j][d0];
      float lt = lsh[0][j] + lsh[1][j] + lsh[2][j] + lsh[3][j];
      float inv = 1.f / lt;
      float4* op = (float4*)(O + bh_base + (long long)(qlo + j) * H + d0);
#pragma unroll
      for (int i = 0; i < 4; i++) {
        float4 s = src[i];
        op[i] = make_float4((acc[qq][4*i+0] + s.x) * inv, (acc[qq][4*i+1] + s.y) * inv,
                            (acc[qq][4*i+2] + s.z) * inv, (acc[qq][4*i+3] + s.w) * inv);
      }
    }
  }
}

// ---------------- rmsnorm2 + router (argmax, fp64) + act_quant ----------------

__global__ __launch_bounds__(256) void k_rms2_router(
    const float* X2, const float* lnw, const float* rw,
    int8_t* xq, double* xsd, int* eidx) {
  __shared__ double tmp[4];
  __shared__ double xn[1024];
  __shared__ double logits[8];
  int t = blockIdx.x, tid = threadIdx.x;
  float4 xv = ((const float4*)(X2 + (long long)t * H))[tid];
  double x0 = xv.x, x1 = xv.y, x2 = xv.z, x3 = xv.w;
  double ss = x0 * x0 + x1 * x1 + x2 * x2 + x3 * x3;
  ss = bredd(ss, 0, tmp);
  double r = 1.0 / sqrt(ss * (1.0 / 1024.0) + 1e-5);
  float4 wv = ((const float4*)lnw)[tid];
  double n0 = x0 * r * wv.x, n1 = x1 * r * wv.y, n2 = x2 * r * wv.z, n3 = x3 * r * wv.w;
  xn[tid * 4 + 0] = n0; xn[tid * 4 + 1] = n1;
  xn[tid * 4 + 2] = n2; xn[tid * 4 + 3] = n3;
  double ma = fmax(fmax(fabs(n0), fabs(n1)), fmax(fabs(n2), fabs(n3)));
  ma = bredd(ma, 1, tmp);  // contains syncthreads -> xn visible
  double s = 127.0 / fmax(ma, 1e-5);
  ((int*)xq)[t * 256 + tid] = qpackd(n0, n1, n2, n3, s);
  if (tid == 0) xsd[t] = s;
  if (tid < 64) {
    int e = tid >> 3, i = tid & 7;
    const float* wr = rw + e * 1024;
    double p = 0.0;
    for (int h = i; h < 1024; h += 8) p += xn[h] * (double)wr[h];
    p += __shfl_xor(p, 1);
    p += __shfl_xor(p, 2);
    p += __shfl_xor(p, 4);
    if (i == 0) logits[e] = p;
  }
  __syncthreads();
  if (tid == 0) {
    double best = logits[0];
    int bi = 0;
    for (int e = 1; e < 8; e++)
      if (logits[e] > best) { best = logits[e]; bi = e; }
    eidx[t] = bi;
  }
}

// ---------------- MoE gate/up: hh[t,d] = relu(g)^2 * u for selected expert ----------------

__global__ __launch_bounds__(256) void k_moe_gu(
    const int8_t* __restrict__ xq, const double* __restrict__ xsd,
    const int* __restrict__ eidx, const int8_t* __restrict__ qw,
    const double* __restrict__ wsd, float* __restrict__ hh) {
  __shared__ int xrow[256];
  int t = blockIdx.x, tid = threadIdx.x;
  xrow[tid] = ((const int*)(xq + (long long)t * H))[tid];
  __syncthreads();
  int e = eidx[t];
  double st = xsd[t];
  double inv_g = 1.0 / (st * wsd[4 + e]);
  double inv_u = 1.0 / (st * wsd[12 + e]);
  const int* gbase = (const int*)qw + ((long long)(4 + e) << 18);
  const int* ubase = (const int*)qw + ((long long)(12 + e) << 18);
  int wid = tid >> 6, lane = tid & 63;
  for (int d = wid; d < DDIM; d += 4) {
    const int* gr = gbase + d * 256;
    const int* ur = ubase + d * 256;
    int ag = 0, au = 0;
#pragma unroll
    for (int c = 0; c < 4; c++) {
      int xc = xrow[lane + c * 64];
      ag = dot4(gr[lane + c * 64], xc, ag);
      au = dot4(ur[lane + c * 64], xc, au);
    }
#pragma unroll
    for (int o = 32; o; o >>= 1) {
      ag += __shfl_xor(ag, o);
      au += __shfl_xor(au, o);
    }
    if (lane == 0) {
      double g = (double)ag * inv_g, u = (double)au * inv_u;
      double rg = fmax(g, 0.0);
      hh[(long long)t * DDIM + d] = (float)(rg * rg * u);
    }
  }
}

// ---------------- MoE down + residual -> final output ----------------

__global__ __launch_bounds__(256) void k_moe_down(
    const int8_t* __restrict__ hq, const double* __restrict__ hsd,
    const int* __restrict__ eidx, const int8_t* __restrict__ qw,
    const double* __restrict__ wsd, const float* __restrict__ x2,
    float* __restrict__ out) {
  __shared__ int xrow[256];
  int t = blockIdx.x, tid = threadIdx.x;
  xrow[tid] = ((const int*)(hq + (long long)t * DDIM))[tid];
  __syncthreads();
  int e = eidx[t];
  double inv = 1.0 / (hsd[t] * wsd[20 + e]);
  const int* dbase = (const int*)qw + ((long long)(20 + e) << 18);
  int wid = tid >> 6, lane = tid & 63;
  for (int h = wid; h < H; h += 4) {
    const int* dr = dbase + h * 256;
    int a = 0;
#pragma unroll
    for (int c = 0; c < 4; c++) a = dot4(dr[lane + c * 64], xrow[lane + c * 64], a);
#pragma unroll
    for (int o = 32; o; o >>= 1) a += __shfl_xor(a, o);
    if (lane == 0)
      out[(long long)t * H + h] = (float)((double)x2[(long long)t * H + h] + (double)a * inv);
  }
}

// ---------------- launch ----------------
// ws layout (bytes):
//   0        partial double[28*1024]  (224 KB)
//   229376   wsd double[28]
//   229600   xsd double[4096] (32 KB)
//   262368   eidx int[4096]
//   278752   Mk float[32]
//   1MB      qw int8: 28 x 1MB
//   32MB     qbuf fp32 16MB (q -> attn out in place)
//   48MB     kbuf fp32 16MB (k -> moe hh)
//   64MB     vbuf fp32 16MB (v -> x2 residual)
//   80MB     xq int8 4MB

extern "C" void kernel_launch(void* const* d_in, const int* in_sizes, int n_in,
                              void* d_out, int out_size, void* d_ws, size_t ws_size,
                              hipStream_t stream) {
  const float* x   = (const float*)d_in[0];
  const float* qw_ = (const float*)d_in[1];
  const float* kw_ = (const float*)d_in[2];
  const float* vw_ = (const float*)d_in[3];
  const float* ow_ = (const float*)d_in[4];
  const float* ln1 = (const float*)d_in[5];
  const float* ln2 = (const float*)d_in[6];
  const float* rw  = (const float*)d_in[7];
  const float* gw  = (const float*)d_in[8];
  const float* uw  = (const float*)d_in[9];
  const float* dw  = (const float*)d_in[10];
  float* out = (float*)d_out;

  uint8_t* ws = (uint8_t*)d_ws;
  double* partial = (double*)ws;
  double* wsd   = (double*)(ws + 229376);
  double* xsd   = (double*)(ws + 229600);
  int*    eidx  = (int*)(ws + 262368);
  float*  Mk    = (float*)(ws + 278752);
  int8_t* qw    = (int8_t*)(ws + (1ull << 20));
  float*  qbuf  = (float*)(ws + (32ull << 20));
  float*  kbuf  = (float*)(ws + (48ull << 20));
  float*  vbuf  = (float*)(ws + (64ull << 20));
  int8_t* xq    = (int8_t*)(ws + (80ull << 20));

  // weight quantization (deterministic fp64 scales)
  k_absum<<<28 * 1024, 256, 0, stream>>>(qw_, kw_, vw_, ow_, gw, uw, dw, partial);
  k_wscale<<<28, 256, 0, stream>>>(partial, wsd);
  k_quantw<<<28 * 1024, 256, 0, stream>>>(qw_, kw_, vw_, ow_, gw, uw, dw, wsd, qw);

  // attention input: rmsnorm + act_quant
  k_rms1<<<NTOK, 256, 0, stream>>>(x, ln1, xq, xsd);
  // q/k/v projections (exact int8 x ternary GEMM)
  k_gemm<<<dim3(16, 64), 256, 0, stream>>>(xq, xsd, qw,             wsd, 0, nullptr, qbuf);
  k_gemm<<<dim3(16, 64), 256, 0, stream>>>(xq, xsd, qw + (1 << 20), wsd, 1, nullptr, kbuf);
  k_gemm<<<dim3(16, 64), 256, 0, stream>>>(xq, xsd, qw + (2 << 20), wsd, 2, nullptr, vbuf);
  // causal flash attention (fixed-bound softmax, key-split waves)
  k_knorm<<<32, 256, 0, stream>>>(kbuf, Mk);
  k_attn<<<dim3(32, NHEAD, 2), 256, 0, stream>>>(qbuf, kbuf, vbuf, qbuf, Mk);
  // o projection with residual: x2 = x + bitlinear(h, o_w) -> vbuf
  k_actq<<<NTOK, 256, 0, stream>>>(qbuf, xq, xsd);
  k_gemm<<<dim3(16, 64), 256, 0, stream>>>(xq, xsd, qw + (3 << 20), wsd, 3, x, vbuf);
  // MoE: rmsnorm2 + router argmax + act_quant
  k_rms2_router<<<NTOK, 256, 0, stream>>>(vbuf, ln2, rw, xq, xsd, eidx);
  k_moe_gu<<<NTOK, 256, 0, stream>>>(xq, xsd, eidx, qw, wsd, kbuf);
  k_actq<<<NTOK, 256, 0, stream>>>(kbuf, xq, xsd);
  k_moe_down<<<NTOK, 256, 0, stream>>>(xq, xsd, eidx, qw, wsd, vbuf, out);
}

// Round 7
// 1241.611 us; speedup vs baseline: 5.5713x; 5.5713x over previous
//
#include <hip/hip_runtime.h>
#include <stdint.h>
#include <math.h>

// Problem constants
#define NTOK 4096   // B*S
#define H    1024
#define NHEAD 16
#define HD   64
#define SEQ  2048
#define NE   8
#define DDIM 1024

// ---------------- helpers ----------------

__device__ __forceinline__ int dot4(int a, int b, int c) {
#if __has_builtin(__builtin_amdgcn_sdot4)
  return __builtin_amdgcn_sdot4(a, b, c, false);
#else
  c += (int)(int8_t)(a)       * (int)(int8_t)(b);
  c += (int)(int8_t)(a >> 8)  * (int)(int8_t)(b >> 8);
  c += (int)(int8_t)(a >> 16) * (int)(int8_t)(b >> 16);
  c += (int)(int8_t)(a >> 24) * (int)(int8_t)(b >> 24);
  return c;
#endif
}

// 256-thread block reduce (double). op=0 sum, op=1 max. tmp: __shared__ double[4]
__device__ __forceinline__ double bredd(double v, int op, double* tmp) {
#pragma unroll
  for (int o = 32; o; o >>= 1) {
    double w = __shfl_xor(v, o);
    v = op ? fmax(v, w) : v + w;
  }
  int wid = threadIdx.x >> 6;
  if ((threadIdx.x & 63) == 0) tmp[wid] = v;
  __syncthreads();
  double r = op ? fmax(fmax(tmp[0], tmp[1]), fmax(tmp[2], tmp[3]))
                : (tmp[0] + tmp[1] + tmp[2] + tmp[3]);
  __syncthreads();
  return r;
}

// quantize 4 doubles to packed int8 with double scale (round-half-even like jnp.round)
__device__ __forceinline__ int qpackd(double n0, double n1, double n2, double n3, double s) {
  int a = (int)fmin(fmax(rint(n0 * s), -128.0), 127.0);
  int b = (int)fmin(fmax(rint(n1 * s), -128.0), 127.0);
  int c = (int)fmin(fmax(rint(n2 * s), -128.0), 127.0);
  int d = (int)fmin(fmax(rint(n3 * s), -128.0), 127.0);
  return (a & 255) | ((b & 255) << 8) | ((c & 255) << 16) | ((d & 255) << 24);
}

// map flat tensor id (0..27, each 1M elems) -> source pointer
__device__ __forceinline__ const float* wsrc(int tensor,
    const float* qw_, const float* kw_, const float* vw_, const float* ow_,
    const float* gw_, const float* uw_, const float* dw_) {
  if (tensor < 4) return tensor == 0 ? qw_ : tensor == 1 ? kw_ : tensor == 2 ? vw_ : ow_;
  if (tensor < 12) return gw_ + ((long long)(tensor - 4) << 20);
  if (tensor < 20) return uw_ + ((long long)(tensor - 12) << 20);
  return dw_ + ((long long)(tensor - 20) << 20);
}

// ---------------- weight quantization (fp64 scale, deterministic) ----------------

__global__ __launch_bounds__(256) void k_absum(
    const float* qw_, const float* kw_, const float* vw_, const float* ow_,
    const float* gw_, const float* uw_, const float* dw_, double* partial) {
  __shared__ double tmp[4];
  int tensor = blockIdx.x >> 10;
  int j = ((blockIdx.x & 1023) << 10) + threadIdx.x * 4;
  const float* src = wsrc(tensor, qw_, kw_, vw_, ow_, gw_, uw_, dw_);
  float4 w = *(const float4*)(src + j);
  double v = fabs((double)w.x) + fabs((double)w.y) + fabs((double)w.z) + fabs((double)w.w);
  v = bredd(v, 0, tmp);
  if (threadIdx.x == 0) partial[blockIdx.x] = v;
}

__global__ __launch_bounds__(256) void k_wscale(const double* partial, double* wsd) {
  __shared__ double tmp[4];
  int tensor = blockIdx.x;
  const double* p = partial + (tensor << 10);
  int i = threadIdx.x * 4;
  double v = p[i] + p[i + 1] + p[i + 2] + p[i + 3];
  v = bredd(v, 0, tmp);
  if (threadIdx.x == 0) wsd[tensor] = 1.0 / fmax(v * (1.0 / 1048576.0), 1e-5);
}

__global__ __launch_bounds__(256) void k_quantw(
    const float* qw_, const float* kw_, const float* vw_, const float* ow_,
    const float* gw_, const float* uw_, const float* dw_,
    const double* wsd, int8_t* qw) {
  int tensor = blockIdx.x >> 10;
  int j = ((blockIdx.x & 1023) << 10) + threadIdx.x * 4;
  const float* src = wsrc(tensor, qw_, kw_, vw_, ow_, gw_, uw_, dw_);
  double s = wsd[tensor];
  float4 w = *(const float4*)(src + j);
  int a = (int)fmin(fmax(rint((double)w.x * s), -1.0), 1.0);
  int b = (int)fmin(fmax(rint((double)w.y * s), -1.0), 1.0);
  int c = (int)fmin(fmax(rint((double)w.z * s), -1.0), 1.0);
  int d = (int)fmin(fmax(rint((double)w.w * s), -1.0), 1.0);
  ((int*)qw)[(tensor << 18) + (j >> 2)] =
      (a & 255) | ((b & 255) << 8) | ((c & 255) << 16) | ((d & 255) << 24);
}

// ---------------- rmsnorm + act_quant (attention input), fp64 decisions ----------------

__global__ __launch_bounds__(256) void k_rms1(const float* X, const float* lnw,
                                              int8_t* xq, double* xsd) {
  __shared__ double tmp[4];
  int t = blockIdx.x, tid = threadIdx.x;
  float4 xv = ((const float4*)(X + (long long)t * H))[tid];
  double x0 = xv.x, x1 = xv.y, x2 = xv.z, x3 = xv.w;
  double ss = x0 * x0 + x1 * x1 + x2 * x2 + x3 * x3;
  ss = bredd(ss, 0, tmp);
  double r = 1.0 / sqrt(ss * (1.0 / 1024.0) + 1e-5);
  float4 wv = ((const float4*)lnw)[tid];
  double n0 = x0 * r * wv.x, n1 = x1 * r * wv.y, n2 = x2 * r * wv.z, n3 = x3 * r * wv.w;
  double ma = fmax(fmax(fabs(n0), fabs(n1)), fmax(fabs(n2), fabs(n3)));
  ma = bredd(ma, 1, tmp);
  double s = 127.0 / fmax(ma, 1e-5);
  ((int*)xq)[t * 256 + tid] = qpackd(n0, n1, n2, n3, s);
  if (tid == 0) xsd[t] = s;
}

// act_quant only (rows of 1024 floats), fp64 decisions
__global__ __launch_bounds__(256) void k_actq(const float* X, int8_t* xq, double* xsd) {
  __shared__ double tmp[4];
  int t = blockIdx.x, tid = threadIdx.x;
  float4 xv = ((const float4*)(X + (long long)t * H))[tid];
  double x0 = xv.x, x1 = xv.y, x2 = xv.z, x3 = xv.w;
  double ma = fmax(fmax(fabs(x0), fabs(x1)), fmax(fabs(x2), fabs(x3)));
  ma = bredd(ma, 1, tmp);
  double s = 127.0 / fmax(ma, 1e-5);
  ((int*)xq)[t * 256 + tid] = qpackd(x0, x1, x2, x3, s);
  if (tid == 0) xsd[t] = s;
}

// ---------------- int8 GEMM: out[t,n] = res[t,n] + acc / (xs[t]*sw) ----------------

__global__ __launch_bounds__(256) void k_gemm(
    const int8_t* __restrict__ Xq, const double* __restrict__ xsd,
    const int8_t* __restrict__ W, const double* __restrict__ wsd, int widx,
    const float* __restrict__ residual, float* __restrict__ out) {
  __shared__ int Xs[32][65];
  __shared__ int Wt[32][65];
  int tid = threadIdx.x;
  int t0 = blockIdx.y * 64, n0 = blockIdx.x * 64;
  const int* Xg = (const int*)Xq;
  const int* Wg = (const int*)W;
  int acc[4][4] = {};
  int lr = tid >> 5, lc = tid & 31;
  int ty = tid >> 4, tx = tid & 15;
  for (int k0 = 0; k0 < 1024; k0 += 128) {
    int kc = k0 >> 2;
#pragma unroll
    for (int i = 0; i < 8; i++) {
      int rr = lr + i * 8;
      Xs[lc][rr] = Xg[(t0 + rr) * 256 + kc + lc];
      Wt[lc][rr] = Wg[(n0 + rr) * 256 + kc + lc];
    }
    __syncthreads();
#pragma unroll
    for (int kk = 0; kk < 32; kk++) {
      int4 a = *(const int4*)&Xs[kk][ty * 4];
      int4 b = *(const int4*)&Wt[kk][tx * 4];
      acc[0][0] = dot4(a.x, b.x, acc[0][0]); acc[0][1] = dot4(a.x, b.y, acc[0][1]);
      acc[0][2] = dot4(a.x, b.z, acc[0][2]); acc[0][3] = dot4(a.x, b.w, acc[0][3]);
      acc[1][0] = dot4(a.y, b.x, acc[1][0]); acc[1][1] = dot4(a.y, b.y, acc[1][1]);
      acc[1][2] = dot4(a.y, b.z, acc[1][2]); acc[1][3] = dot4(a.y, b.w, acc[1][3]);
      acc[2][0] = dot4(a.z, b.x, acc[2][0]); acc[2][1] = dot4(a.z, b.y, acc[2][1]);
      acc[2][2] = dot4(a.z, b.z, acc[2][2]); acc[2][3] = dot4(a.z, b.w, acc[2][3]);
      acc[3][0] = dot4(a.w, b.x, acc[3][0]); acc[3][1] = dot4(a.w, b.y, acc[3][1]);
      acc[3][2] = dot4(a.w, b.z, acc[3][2]); acc[3][3] = dot4(a.w, b.w, acc[3][3]);
    }
    __syncthreads();
  }
  double sw = wsd[widx];
#pragma unroll
  for (int i = 0; i < 4; i++) {
    int t = t0 + ty * 4 + i;
    double inv = 1.0 / (xsd[t] * sw);
#pragma unroll
    for (int j = 0; j < 4; j++) {
      int n = n0 + tx * 4 + j;
      double v = (double)acc[i][j] * inv;
      if (residual) v += (double)residual[(long long)t * H + n];
      out[(long long)t * H + n] = (float)v;
    }
  }
}

// ---------------- attention ----------------
// k_knorm: per-(b,head) max key L2-norm -> fixed softmax bound.

__global__ __launch_bounds__(256) void k_knorm(const float* __restrict__ K,
                                               float* __restrict__ Mk) {
  __shared__ float tmp[4];
  int bh = blockIdx.x;          // b*16 + head
  int b = bh >> 4, head = bh & 15;
  int tid = threadIdx.x;
  float mx = 0.f;
  for (int key = tid; key < SEQ; key += 256) {
    const float4* kr = (const float4*)(K + ((long long)(b * SEQ + key)) * H + head * HD);
    float s = 0.f;
#pragma unroll
    for (int i = 0; i < 16; i++) {
      float4 v = kr[i];
      s += v.x * v.x + v.y * v.y + v.z * v.z + v.w * v.w;
    }
    mx = fmaxf(mx, s);
  }
#pragma unroll
  for (int o = 32; o; o >>= 1) mx = fmaxf(mx, __shfl_xor(mx, o));
  if ((tid & 63) == 0) tmp[tid >> 6] = mx;
  __syncthreads();
  if (tid == 0)
    Mk[bh] = sqrtf(fmaxf(fmaxf(tmp[0], tmp[1]), fmaxf(tmp[2], tmp[3])));
}

// k_attn: grid (32 qtiles reversed, 16 heads, 2 b), block 256 = 4 waves, 64 q/block.
// K/V tiles STAGED in LDS (R5-style); the 4 waves split the staged tile:
// wave w: query-half qh=w>>1 (32 queries), key parity ks=w&1 (32 of 64 keys).
// -> 4096 waves = 4/SIMD. Lane = quad*4+dp: quad owns 2 queries, dp owns 16 dims.
// Fixed-bound softmax (R6, validated): wgt = exp(p - 0.125*|q|*maxk|k|); no serial
// max-chain, partials merge by plain sums. Merge reuses the dead K-tile LDS.

__global__ __launch_bounds__(256) void k_attn(
    const float* __restrict__ Q, const float* __restrict__ K,
    const float* __restrict__ V, float* __restrict__ O,
    const float* __restrict__ Mk) {
  __shared__ float smem[2][64][68];   // Ks=smem[0], Vs=smem[1]; merge aliases smem[0]
  __shared__ float lsh[4][32];
  int g = 31 - blockIdx.x;            // longest blocks dispatch first
  int head = blockIdx.y, b = blockIdx.z;
  int tid = threadIdx.x;
  int w = tid >> 6, lane = tid & 63;
  int qh = w >> 1, ks = w & 1;
  int quad = lane >> 2, dp = lane & 3;
  int qlo = g * 64;
  int d0 = dp << 4;
  long long bh_base = ((long long)b * SEQ) * H + head * HD;

  // load 2 queries (quad-local), compute fixed bound mb
  float4 q[2][4];
  float mb[2], l[2] = {0.f, 0.f};
  float acc[2][16];
#pragma unroll
  for (int qq = 0; qq < 2; qq++)
#pragma unroll
    for (int i = 0; i < 16; i++) acc[qq][i] = 0.f;
  float mkv = Mk[b * 16 + head];
#pragma unroll
  for (int qq = 0; qq < 2; qq++) {
    int j = qh * 32 + quad * 2 + qq;                  // local query 0..63
    const float4* qp = (const float4*)(Q + bh_base + (long long)(qlo + j) * H + d0);
    float ss = 0.f;
#pragma unroll
    for (int i = 0; i < 4; i++) {
      float4 t = qp[i];
      q[qq][i] = make_float4(t.x * 0.125f, t.y * 0.125f, t.z * 0.125f, t.w * 0.125f);
      ss += t.x * t.x + t.y * t.y + t.z * t.z + t.w * t.w;
    }
    ss += __shfl_xor(ss, 1);
    ss += __shfl_xor(ss, 2);
    mb[qq] = 0.125f * sqrtf(ss) * mkv;
  }

  int srow = tid >> 2;               // staging: key row 0..63
  int sdc = (tid & 3) << 4;          // staging: d chunk 0/16/32/48

  for (int t = 0; t <= g; t++) {
    long long srowg = bh_base + (long long)(t * 64 + srow) * H + sdc;
    const float4* kg = (const float4*)(K + srowg);
    const float4* vg = (const float4*)(V + srowg);
    float4* ksd = (float4*)&smem[0][srow][sdc];
    float4* vsd = (float4*)&smem[1][srow][sdc];
#pragma unroll
    for (int i = 0; i < 4; i++) ksd[i] = kg[i];
#pragma unroll
    for (int i = 0; i < 4; i++) vsd[i] = vg[i];
    __syncthreads();

    int kend = (t < g) ? 64 : (qh * 32 + 32);   // diagonal: qh=0 waves skip keys>=32
    for (int kk = ks; kk < kend; kk += 2) {
      const float4* kr = (const float4*)&smem[0][kk][d0];
      float4 kv0 = kr[0], kv1 = kr[1], kv2 = kr[2], kv3 = kr[3];
      float p[2];
#pragma unroll
      for (int qq = 0; qq < 2; qq++) {
        float pa = 0.f, pb = 0.f;
        pa = fmaf(q[qq][0].x, kv0.x, pa); pb = fmaf(q[qq][0].y, kv0.y, pb);
        pa = fmaf(q[qq][0].z, kv0.z, pa); pb = fmaf(q[qq][0].w, kv0.w, pb);
        pa = fmaf(q[qq][1].x, kv1.x, pa); pb = fmaf(q[qq][1].y, kv1.y, pb);
        pa = fmaf(q[qq][1].z, kv1.z, pa); pb = fmaf(q[qq][1].w, kv1.w, pb);
        pa = fmaf(q[qq][2].x, kv2.x, pa); pb = fmaf(q[qq][2].y, kv2.y, pb);
        pa = fmaf(q[qq][2].z, kv2.z, pa); pb = fmaf(q[qq][2].w, kv2.w, pb);
        pa = fmaf(q[qq][3].x, kv3.x, pa); pb = fmaf(q[qq][3].y, kv3.y, pb);
        pa = fmaf(q[qq][3].z, kv3.z, pa); pb = fmaf(q[qq][3].w, kv3.w, pb);
        float pp = pa + pb;
        pp += __shfl_xor(pp, 1);
        pp += __shfl_xor(pp, 2);
        p[qq] = pp;
      }
      const float4* vr = (const float4*)&smem[1][kk][d0];
      float4 vv0 = vr[0], vv1 = vr[1], vv2 = vr[2], vv3 = vr[3];
#pragma unroll
      for (int qq = 0; qq < 2; qq++) {
        int j = qh * 32 + quad * 2 + qq;
        bool ok = (t < g) || (kk <= j);
        float wgt = ok ? __expf(p[qq] - mb[qq]) : 0.f;
        l[qq] += wgt;
        acc[qq][0]  = fmaf(wgt, vv0.x, acc[qq][0]);
        acc[qq][1]  = fmaf(wgt, vv0.y, acc[qq][1]);
        acc[qq][2]  = fmaf(wgt, vv0.z, acc[qq][2]);
        acc[qq][3]  = fmaf(wgt, vv0.w, acc[qq][3]);
        acc[qq][4]  = fmaf(wgt, vv1.x, acc[qq][4]);
        acc[qq][5]  = fmaf(wgt, vv1.y, acc[qq][5]);
        acc[qq][6]  = fmaf(wgt, vv1.z, acc[qq][6]);
        acc[qq][7]  = fmaf(wgt, vv1.w, acc[qq][7]);
        acc[qq][8]  = fmaf(wgt, vv2.x, acc[qq][8]);
        acc[qq][9]  = fmaf(wgt, vv2.y, acc[qq][9]);
        acc[qq][10] = fmaf(wgt, vv2.z, acc[qq][10]);
        acc[qq][11] = fmaf(wgt, vv2.w, acc[qq][11]);
        acc[qq][12] = fmaf(wgt, vv3.x, acc[qq][12]);
        acc[qq][13] = fmaf(wgt, vv3.y, acc[qq][13]);
        acc[qq][14] = fmaf(wgt, vv3.z, acc[qq][14]);
        acc[qq][15] = fmaf(wgt, vv3.w, acc[qq][15]);
      }
    }
    __syncthreads();
  }

  // ---- merge (fixed bound => plain sums). smem[0] (K tile) is dead; alias it.
  float (*mrg)[68] = smem[0];        // 64 rows: rows 0..31 <- wave1, 32..63 <- wave3
  if (dp == 0) {
    lsh[w][quad * 2 + 0] = l[0];
    lsh[w][quad * 2 + 1] = l[1];
  }
  if (ks == 1) {                     // waves 1,3 publish partial acc
#pragma unroll
    for (int qq = 0; qq < 2; qq++) {
      int row = qh * 32 + quad * 2 + qq;
      float4* dst = (float4*)&mrg[row][d0];
#pragma unroll
      for (int i = 0; i < 4; i++)
        dst[i] = make_float4(acc[qq][4*i], acc[qq][4*i+1], acc[qq][4*i+2], acc[qq][4*i+3]);
    }
  }
  __syncthreads();
  if (ks == 0) {                     // waves 0,2: sum, normalize, store
#pragma unroll
    for (int qq = 0; qq < 2; qq++) {
      int jl = quad * 2 + qq;        // 0..31 within half
      int row = qh * 32 + jl;
      float lt = lsh[w][jl] + lsh[w + 1][jl];
      float inv = 1.f / lt;
      const float4* src = (const float4*)&mrg[row][d0];
      float4* op = (float4*)(O + bh_base + (long long)(qlo + row) * H + d0);
#pragma unroll
      for (int i = 0; i < 4; i++) {
        float4 s = src[i];
        op[i] = make_float4((acc[qq][4*i+0] + s.x) * inv, (acc[qq][4*i+1] + s.y) * inv,
                            (acc[qq][4*i+2] + s.z) * inv, (acc[qq][4*i+3] + s.w) * inv);
      }
    }
  }
}

// ---------------- rmsnorm2 + router (argmax, fp64) + act_quant ----------------

__global__ __launch_bounds__(256) void k_rms2_router(
    const float* X2, const float* lnw, const float* rw,
    int8_t* xq, double* xsd, int* eidx) {
  __shared__ double tmp[4];
  __shared__ double xn[1024];
  __shared__ double logits[8];
  int t = blockIdx.x, tid = threadIdx.x;
  float4 xv = ((const float4*)(X2 + (long long)t * H))[tid];
  double x0 = xv.x, x1 = xv.y, x2 = xv.z, x3 = xv.w;
  double ss = x0 * x0 + x1 * x1 + x2 * x2 + x3 * x3;
  ss = bredd(ss, 0, tmp);
  double r = 1.0 / sqrt(ss * (1.0 / 1024.0) + 1e-5);
  float4 wv = ((const float4*)lnw)[tid];
  double n0 = x0 * r * wv.x, n1 = x1 * r * wv.y, n2 = x2 * r * wv.z, n3 = x3 * r * wv.w;
  xn[tid * 4 + 0] = n0; xn[tid * 4 + 1] = n1;
  xn[tid * 4 + 2] = n2; xn[tid * 4 + 3] = n3;
  double ma = fmax(fmax(fabs(n0), fabs(n1)), fmax(fabs(n2), fabs(n3)));
  ma = bredd(ma, 1, tmp);  // contains syncthreads -> xn visible
  double s = 127.0 / fmax(ma, 1e-5);
  ((int*)xq)[t * 256 + tid] = qpackd(n0, n1, n2, n3, s);
  if (tid == 0) xsd[t] = s;
  if (tid < 64) {
    int e = tid >> 3, i = tid & 7;
    const float* wr = rw + e * 1024;
    double p = 0.0;
    for (int h = i; h < 1024; h += 8) p += xn[h] * (double)wr[h];
    p += __shfl_xor(p, 1);
    p += __shfl_xor(p, 2);
    p += __shfl_xor(p, 4);
    if (i == 0) logits[e] = p;
  }
  __syncthreads();
  if (tid == 0) {
    double best = logits[0];
    int bi = 0;
    for (int e = 1; e < 8; e++)
      if (logits[e] > best) { best = logits[e]; bi = e; }
    eidx[t] = bi;
  }
}

// ---------------- MoE routing: group tokens by expert into padded 64-slot tiles ----
// meta[0] = ntile; meta[1+i] = expert of tile i. tokidx[slot] = token or -1 (pad).

__global__ __launch_bounds__(256) void k_route(const int* __restrict__ eidx,
                                               int* __restrict__ meta,
                                               int* __restrict__ tokidx) {
  __shared__ int cnt[8], pb[9], cur[8];
  int tid = threadIdx.x;
  if (tid < 8) cnt[tid] = 0;
  __syncthreads();
  for (int t = tid; t < NTOK; t += 256) atomicAdd(&cnt[eidx[t]], 1);
  __syncthreads();
  if (tid == 0) {
    pb[0] = 0;
    int nt = 0;
    for (int e = 0; e < 8; e++) {
      int tiles = (cnt[e] + 63) >> 6;
      for (int i = 0; i < tiles; i++) meta[1 + nt + i] = e;
      nt += tiles;
      pb[e + 1] = pb[e] + tiles * 64;
      cur[e] = pb[e];
    }
    meta[0] = nt;
  }
  __syncthreads();
  for (int s = tid; s < 4608; s += 256) tokidx[s] = -1;
  __syncthreads();
  for (int t = tid; t < NTOK; t += 256) {
    int e = eidx[t];
    int s = atomicAdd(&cur[e], 1);
    tokidx[s] = t;
  }
}

// ---------------- MoE gate+up GEMM -> hh (fused relu(g)^2*u) ----------------
// grid (16 n-tiles, 71 slot-tiles). Gathered X rows; two W tiles per block.

__global__ __launch_bounds__(256) void k_moe_gu(
    const int8_t* __restrict__ Xq, const double* __restrict__ xsd,
    const int8_t* __restrict__ qw, const double* __restrict__ wsd,
    const int* __restrict__ meta, const int* __restrict__ tokidx,
    float* __restrict__ hhbuf) {
  __shared__ int Xs[32][65];
  __shared__ int Wg[32][65];
  __shared__ int Wu[32][65];
  int tile = blockIdx.y;
  if (tile >= meta[0]) return;
  int e = meta[1 + tile];
  int n0 = blockIdx.x * 64;
  int s0 = tile * 64;
  int tid = threadIdx.x;
  int lr = tid >> 5, lc = tid & 31;
  int ty = tid >> 4, tx = tid & 15;
  const int* Xg = (const int*)Xq;
  const int* Gg = (const int*)(qw + ((long long)(4 + e) << 20));
  const int* Ug = (const int*)(qw + ((long long)(12 + e) << 20));
  int toks[8];
#pragma unroll
  for (int i = 0; i < 8; i++) {
    int tk = tokidx[s0 + lr + i * 8];
    toks[i] = tk < 0 ? 0 : tk;
  }
  int accg[4][4] = {};
  int accu[4][4] = {};
  for (int k0 = 0; k0 < 1024; k0 += 128) {
    int kc = k0 >> 2;
#pragma unroll
    for (int i = 0; i < 8; i++) {
      int rr = lr + i * 8;
      Xs[lc][rr] = Xg[toks[i] * 256 + kc + lc];
      Wg[lc][rr] = Gg[(n0 + rr) * 256 + kc + lc];
      Wu[lc][rr] = Ug[(n0 + rr) * 256 + kc + lc];
    }
    __syncthreads();
#pragma unroll
    for (int kk = 0; kk < 32; kk++) {
      int4 a  = *(const int4*)&Xs[kk][ty * 4];
      int4 bg = *(const int4*)&Wg[kk][tx * 4];
      int4 bu = *(const int4*)&Wu[kk][tx * 4];
      accg[0][0] = dot4(a.x, bg.x, accg[0][0]); accg[0][1] = dot4(a.x, bg.y, accg[0][1]);
      accg[0][2] = dot4(a.x, bg.z, accg[0][2]); accg[0][3] = dot4(a.x, bg.w, accg[0][3]);
      accg[1][0] = dot4(a.y, bg.x, accg[1][0]); accg[1][1] = dot4(a.y, bg.y, accg[1][1]);
      accg[1][2] = dot4(a.y, bg.z, accg[1][2]); accg[1][3] = dot4(a.y, bg.w, accg[1][3]);
      accg[2][0] = dot4(a.z, bg.x, accg[2][0]); accg[2][1] = dot4(a.z, bg.y, accg[2][1]);
      accg[2][2] = dot4(a.z, bg.z, accg[2][2]); accg[2][3] = dot4(a.z, bg.w, accg[2][3]);
      accg[3][0] = dot4(a.w, bg.x, accg[3][0]); accg[3][1] = dot4(a.w, bg.y, accg[3][1]);
      accg[3][2] = dot4(a.w, bg.z, accg[3][2]); accg[3][3] = dot4(a.w, bg.w, accg[3][3]);
      accu[0][0] = dot4(a.x, bu.x, accu[0][0]); accu[0][1] = dot4(a.x, bu.y, accu[0][1]);
      accu[0][2] = dot4(a.x, bu.z, accu[0][2]); accu[0][3] = dot4(a.x, bu.w, accu[0][3]);
      accu[1][0] = dot4(a.y, bu.x, accu[1][0]); accu[1][1] = dot4(a.y, bu.y, accu[1][1]);
      accu[1][2] = dot4(a.y, bu.z, accu[1][2]); accu[1][3] = dot4(a.y, bu.w, accu[1][3]);
      accu[2][0] = dot4(a.z, bu.x, accu[2][0]); accu[2][1] = dot4(a.z, bu.y, accu[2][1]);
      accu[2][2] = dot4(a.z, bu.z, accu[2][2]); accu[2][3] = dot4(a.z, bu.w, accu[2][3]);
      accu[3][0] = dot4(a.w, bu.x, accu[3][0]); accu[3][1] = dot4(a.w, bu.y, accu[3][1]);
      accu[3][2] = dot4(a.w, bu.z, accu[3][2]); accu[3][3] = dot4(a.w, bu.w, accu[3][3]);
    }
    __syncthreads();
  }
  double swg = wsd[4 + e], swu = wsd[12 + e];
#pragma unroll
  for (int i = 0; i < 4; i++) {
    int s = s0 + ty * 4 + i;
    int tok = tokidx[s];
    if (tok < 0) continue;
    double ig = 1.0 / (xsd[tok] * swg);
    double iu = 1.0 / (xsd[tok] * swu);
#pragma unroll
    for (int j = 0; j < 4; j++) {
      int n = n0 + tx * 4 + j;
      double g = (double)accg[i][j] * ig;
      double u = (double)accu[i][j] * iu;
      double rg = fmax(g, 0.0);
      hhbuf[(long long)s * DDIM + n] = (float)(rg * rg * u);
    }
  }
}

// ---------------- act_quant over hh slot rows ----------------

__global__ __launch_bounds__(256) void k_hh_actq(
    const float* __restrict__ hhbuf, const int* __restrict__ meta,
    const int* __restrict__ tokidx, int8_t* __restrict__ hq,
    double* __restrict__ hsd) {
  __shared__ double tmp[4];
  int s = blockIdx.x;
  if (s >= meta[0] * 64) return;
  int tid = threadIdx.x;
  int tok = tokidx[s];
  if (tok < 0) {
    ((int*)hq)[s * 256 + tid] = 0;
    if (tid == 0) hsd[s] = 1.0;
    return;
  }
  float4 xv = ((const float4*)(hhbuf + (long long)s * DDIM))[tid];
  double x0 = xv.x, x1 = xv.y, x2 = xv.z, x3 = xv.w;
  double ma = fmax(fmax(fabs(x0), fabs(x1)), fmax(fabs(x2), fabs(x3)));
  ma = bredd(ma, 1, tmp);
  double sc = 127.0 / fmax(ma, 1e-5);
  ((int*)hq)[s * 256 + tid] = qpackd(x0, x1, x2, x3, sc);
  if (tid == 0) hsd[s] = sc;
}

// ---------------- MoE down GEMM + residual -> out (scatter) ----------------

__global__ __launch_bounds__(256) void k_moe_down(
    const int8_t* __restrict__ hq, const double* __restrict__ hsd,
    const int8_t* __restrict__ qw, const double* __restrict__ wsd,
    const int* __restrict__ meta, const int* __restrict__ tokidx,
    const float* __restrict__ x2, float* __restrict__ out) {
  __shared__ int Xs[32][65];
  __shared__ int Wt[32][65];
  int tile = blockIdx.y;
  if (tile >= meta[0]) return;
  int e = meta[1 + tile];
  int n0 = blockIdx.x * 64;
  int s0 = tile * 64;
  int tid = threadIdx.x;
  int lr = tid >> 5, lc = tid & 31;
  int ty = tid >> 4, tx = tid & 15;
  const int* Xg = (const int*)hq;
  const int* Wg = (const int*)(qw + ((long long)(20 + e) << 20));
  int acc[4][4] = {};
  for (int k0 = 0; k0 < 1024; k0 += 128) {
    int kc = k0 >> 2;
#pragma unroll
    for (int i = 0; i < 8; i++) {
      int rr = lr + i * 8;
      Xs[lc][rr] = Xg[(s0 + rr) * 256 + kc + lc];
      Wt[lc][rr] = Wg[(n0 + rr) * 256 + kc + lc];
    }
    __syncthreads();
#pragma unroll
    for (int kk = 0; kk < 32; kk++) {
      int4 a = *(const int4*)&Xs[kk][ty * 4];
      int4 b = *(const int4*)&Wt[kk][tx * 4];
      acc[0][0] = dot4(a.x, b.x, acc[0][0]); acc[0][1] = dot4(a.x, b.y, acc[0][1]);
      acc[0][2] = dot4(a.x, b.z, acc[0][2]); acc[0][3] = dot4(a.x, b.w, acc[0][3]);
      acc[1][0] = dot4(a.y, b.x, acc[1][0]); acc[1][1] = dot4(a.y, b.y, acc[1][1]);
      acc[1][2] = dot4(a.y, b.z, acc[1][2]); acc[1][3] = dot4(a.y, b.w, acc[1][3]);
      acc[2][0] = dot4(a.z, b.x, acc[2][0]); acc[2][1] = dot4(a.z, b.y, acc[2][1]);
      acc[2][2] = dot4(a.z, b.z, acc[2][2]); acc[2][3] = dot4(a.z, b.w, acc[2][3]);
      acc[3][0] = dot4(a.w, b.x, acc[3][0]); acc[3][1] = dot4(a.w, b.y, acc[3][1]);
      acc[3][2] = dot4(a.w, b.z, acc[3][2]); acc[3][3] = dot4(a.w, b.w, acc[3][3]);
    }
    __syncthreads();
  }
  double sw = wsd[20 + e];
#pragma unroll
  for (int i = 0; i < 4; i++) {
    int s = s0 + ty * 4 + i;
    int tok = tokidx[s];
    if (tok < 0) continue;
    double inv = 1.0 / (hsd[s] * sw);
#pragma unroll
    for (int j = 0; j < 4; j++) {
      int n = n0 + tx * 4 + j;
      out[(long long)tok * H + n] =
          (float)((double)x2[(long long)tok * H + n] + (double)acc[i][j] * inv);
    }
  }
}

// ---------------- launch ----------------
// ws layout (bytes):
//   0        partial double[28*1024] (224 KB)
//   229376   wsd double[28]
//   229600   xsd double[4096] (32 KB)
//   262368   eidx int[4096] (16 KB)
//   278752   Mk float[32]
//   278912   meta int[128]  (ntile + tile_e)
//   279424   tokidx int[4608] (18 KB)
//   297856   hsd double[4608] (36.9 KB)
//   1MB      qw int8: 28 x 1MB
//   29MB     xq int8 4MB
//   33MB     qbuf fp32 16MB (q -> attn out h); later hhbuf f32 [4544][1024] (18.6MB, 33..51.6)
//   49MB     kbuf fp32 16MB (k; dead after attn)
//   52MB     hq int8 [4544][1024] (4.65MB, 52..56.7)   <- inside dead kbuf region
//   65MB     vbuf fp32 16MB (v -> x2 residual)

extern "C" void kernel_launch(void* const* d_in, const int* in_sizes, int n_in,
                              void* d_out, int out_size, void* d_ws, size_t ws_size,
                              hipStream_t stream) {
  const float* x   = (const float*)d_in[0];
  const float* qw_ = (const float*)d_in[1];
  const float* kw_ = (const float*)d_in[2];
  const float* vw_ = (const float*)d_in[3];
  const float* ow_ = (const float*)d_in[4];
  const float* ln1 = (const float*)d_in[5];
  const float* ln2 = (const float*)d_in[6];
  const float* rw  = (const float*)d_in[7];
  const float* gw  = (const float*)d_in[8];
  const float* uw  = (const float*)d_in[9];
  const float* dw  = (const float*)d_in[10];
  float* out = (float*)d_out;

  uint8_t* ws = (uint8_t*)d_ws;
  double* partial = (double*)ws;
  double* wsd    = (double*)(ws + 229376);
  double* xsd    = (double*)(ws + 229600);
  int*    eidx   = (int*)(ws + 262368);
  float*  Mk     = (float*)(ws + 278752);
  int*    meta   = (int*)(ws + 278912);
  int*    tokidx = (int*)(ws + 279424);
  double* hsd    = (double*)(ws + 297856);
  int8_t* qw     = (int8_t*)(ws + (1ull << 20));
  int8_t* xq     = (int8_t*)(ws + (29ull << 20));
  float*  qbuf   = (float*)(ws + (33ull << 20));
  float*  hhbuf  = (float*)(ws + (33ull << 20));   // aliases qbuf (dead by then)
  float*  kbuf   = (float*)(ws + (49ull << 20));
  int8_t* hq     = (int8_t*)(ws + (52ull << 20));  // inside dead kbuf region
  float*  vbuf   = (float*)(ws + (65ull << 20));

  // weight quantization (deterministic fp64 scales)
  k_absum<<<28 * 1024, 256, 0, stream>>>(qw_, kw_, vw_, ow_, gw, uw, dw, partial);
  k_wscale<<<28, 256, 0, stream>>>(partial, wsd);
  k_quantw<<<28 * 1024, 256, 0, stream>>>(qw_, kw_, vw_, ow_, gw, uw, dw, wsd, qw);

  // attention input: rmsnorm + act_quant
  k_rms1<<<NTOK, 256, 0, stream>>>(x, ln1, xq, xsd);
  // q/k/v projections (exact int8 x ternary GEMM)
  k_gemm<<<dim3(16, 64), 256, 0, stream>>>(xq, xsd, qw,             wsd, 0, nullptr, qbuf);
  k_gemm<<<dim3(16, 64), 256, 0, stream>>>(xq, xsd, qw + (1 << 20), wsd, 1, nullptr, kbuf);
  k_gemm<<<dim3(16, 64), 256, 0, stream>>>(xq, xsd, qw + (2 << 20), wsd, 2, nullptr, vbuf);
  // causal flash attention (fixed-bound softmax, staged K/V, key-split waves)
  k_knorm<<<32, 256, 0, stream>>>(kbuf, Mk);
  k_attn<<<dim3(32, NHEAD, 2), 256, 0, stream>>>(qbuf, kbuf, vbuf, qbuf, Mk);
  // o projection with residual: x2 = x + bitlinear(h, o_w) -> vbuf
  k_actq<<<NTOK, 256, 0, stream>>>(qbuf, xq, xsd);
  k_gemm<<<dim3(16, 64), 256, 0, stream>>>(xq, xsd, qw + (3 << 20), wsd, 3, x, vbuf);
  // MoE: rmsnorm2 + router argmax + act_quant, then expert-gathered GEMMs
  k_rms2_router<<<NTOK, 256, 0, stream>>>(vbuf, ln2, rw, xq, xsd, eidx);
  k_route<<<1, 256, 0, stream>>>(eidx, meta, tokidx);
  k_moe_gu<<<dim3(16, 71), 256, 0, stream>>>(xq, xsd, qw, wsd, meta, tokidx, hhbuf);
  k_hh_actq<<<4544, 256, 0, stream>>>(hhbuf, meta, tokidx, hq, hsd);
  k_moe_down<<<dim3(16, 71), 256, 0, stream>>>(hq, hsd, qw, wsd, meta, tokidx, vbuf, out);
}